// Round 1
// baseline (328.625 us; speedup 1.0000x reference)
//
#include <hip/hip_runtime.h>

// Bilinear 2x upsample, NHWC fp32.
// in : (8, 256, 256, 32)  = 64 MiB
// out: (8, 512, 512, 32)  = 256 MiB
//
// R2: two output pixels (oy = 2j, 2j+1) per thread; 6 float4 loads + 2 stores.
// R3 (this round):
//  (a) XCD-aware bijective block swizzle. Default round-robin dispatch makes
//      every XCD sweep all (n, j) -> each of 8 XCDs streams the full 64 MiB
//      input through its private L2, and the 268 MB write stream thrashes L3,
//      so cross-XCD re-reads miss to HBM (~512 MB read amplification).
//      Swizzle gives each XCD a contiguous work chunk == exactly one image n
//      (8 MiB input slice, 3-row reuse window fits its 4 MiB L2).
//  (b) Non-temporal stores: output is never re-read; keep the write stream
//      from evicting input lines in L2/L3.

#define IH 256
#define IW 256
#define OHW 512
#define C4 8        // 32 channels / 4 floats per float4
#define NBLK 32768u // total blocks; 32768 % 8 == 0 -> swizzle is bijective

typedef float f4 __attribute__((ext_vector_type(4)));

__global__ __launch_bounds__(256) void bilinear2x_kernel(
    const float* __restrict__ img, float* __restrict__ out) {
    // XCD swizzle: XCD x (= blockIdx%8 under round-robin dispatch) gets the
    // contiguous work range [x*4096, (x+1)*4096) -> n == x for that XCD.
    unsigned b  = blockIdx.x;
    unsigned wb = (b & 7u) * (NBLK / 8u) + (b >> 3);
    unsigned tid = wb * 256u + threadIdx.x;

    unsigned c4 = tid & (C4 - 1);          // float4 index within channels
    unsigned ox = (tid >> 3) & (OHW - 1);  // output x
    unsigned j  = (tid >> 12) & (IH - 1);  // output y pair index: oy = 2j, 2j+1
    unsigned n  = tid >> 20;

    // x weights: gx = max(0.5*ox - 0.25, 0)
    float gx = fmaxf(0.5f * (float)ox - 0.25f, 0.0f);
    int x0 = (int)gx;                      // trunc == floor (gx >= 0)
    float w0 = gx - (float)x0;
    int x1 = x0 + (x0 < IW - 1);
    float w1 = 1.0f - w0;

    // input rows j-1, j, j+1 (clamped). Clamping reproduces the reference
    // edge cases: j=0 -> even output = row0 exactly; j=255 -> odd = row255.
    int rA = (int)j - 1; rA = rA < 0 ? 0 : rA;
    int rB = (int)j;
    int rC = (int)j + 1; rC = rC > IH - 1 ? IH - 1 : rC;

    const f4* base = (const f4*)img;
    size_t nb = (size_t)n * (IH * IW * C4);
    const f4* pA = base + nb + (size_t)rA * (IW * C4);
    const f4* pB = base + nb + (size_t)rB * (IW * C4);
    const f4* pC = base + nb + (size_t)rC * (IW * C4);
    size_t o0 = (size_t)x0 * C4 + c4;
    size_t o1 = (size_t)x1 * C4 + c4;

    f4 a0 = pA[o0], a1 = pA[o1];
    f4 b0 = pB[o0], b1 = pB[o1];
    f4 c0 = pC[o0], c1 = pC[o1];

    // x-interpolate each row
    f4 ra = w1 * a0 + w0 * a1;
    f4 rb = w1 * b0 + w0 * b1;
    f4 rc = w1 * c0 + w0 * c1;

    // y-combine with constant weights:
    // even (oy=2j):   0.25*rowA + 0.75*rowB
    // odd  (oy=2j+1): 0.75*rowB + 0.25*rowC
    f4 re = 0.25f * ra + 0.75f * rb;
    f4 ro = 0.75f * rb + 0.25f * rc;

    // stores: out[(n, 2j, ox, c4)] and out[(n, 2j+1, ox, c4)] — non-temporal
    f4* ob = (f4*)out;
    size_t oe = (((size_t)n * OHW + 2 * j) * OHW + ox) * C4 + c4;
    __builtin_nontemporal_store(re, ob + oe);
    __builtin_nontemporal_store(ro, ob + oe + (size_t)OHW * C4);
}

extern "C" void kernel_launch(void* const* d_in, const int* in_sizes, int n_in,
                              void* d_out, int out_size, void* d_ws, size_t ws_size,
                              hipStream_t stream) {
    const float* img = (const float*)d_in[0];
    float* out = (float*)d_out;
    // threads: 8 * 256(j) * 512(ox) * 8(c4) = 8,388,608 -> 32768 blocks
    dim3 grid(NBLK);
    dim3 block(256);
    bilinear2x_kernel<<<grid, block, 0, stream>>>(img, out);
}